// Round 4
// baseline (93881.567 us; speedup 1.0000x reference)
//
#include <hip/hip_runtime.h>
#include <stdint.h>

// LSTMEncoder: T=8192, IN_DIM=512, H=1024, 2 layers, fp32.
// Phases (all on `stream`, serialized by stream order):
//   1. nan_fill(h1), nan_fill(d_out)          -- sentinel init (system-scope stores)
//   2. gemm: xg = x @ W_ih_0 + b_0            -- [8192,512]@[512,4096]
//   3. scan layer 0 -> h1 (persistent dataflow, sentinel sync)
//   4. gemm: xg = h1 @ W_ih_1 + b_1           -- [8192,1024]@[1024,4096]
//   5. scan layer 1 -> d_out
// Workspace: xg (128 MB) + h1 (32 MB) = 160 MB.

#define TT    8192
#define INDIM 512
#define HH    1024
#define G4    4096   // 4*H

#define SENT 0x7FC00000u  // NaN sentinel bit pattern

typedef float f32x4 __attribute__((ext_vector_type(4)));  // native vec -> direct VGPR tuple for asm "v"

__device__ __forceinline__ float sigf(float x) { return 1.0f / (1.0f + __expf(-x)); }

// ---------------------------------------------------------------------------
// Sentinel init: fill region with NaN using system-scope stores (no dirty
// L2-only lines that could later mask the producer's h values).
// ---------------------------------------------------------------------------
__global__ void nan_fill_kernel(float* __restrict__ p, long n) {
  float sv = __uint_as_float(SENT);
  long i = (long)blockIdx.x * blockDim.x + threadIdx.x;
  long stride = (long)gridDim.x * blockDim.x;
  for (; i < n; i += stride) {
    __hip_atomic_store(p + i, sv, __ATOMIC_RELAXED, __HIP_MEMORY_SCOPE_SYSTEM);
  }
}

// ---------------------------------------------------------------------------
// fp32 GEMM with bias: C[M,N] = A[M,K] @ B[K,N] + bias[N]
// BM=BN=128, BK=16, 256 threads, 8x8 per thread. M%128==0, N%128==0, K%16==0.
// ---------------------------------------------------------------------------
__global__ __launch_bounds__(256, 2) void gemm_bias_f32(
    const float* __restrict__ A, const float* __restrict__ B,
    const float* __restrict__ bias, float* __restrict__ C,
    int M, int N, int K)
{
  constexpr int BM = 128, BN = 128, BK = 16, TM = 8, TN = 8;
  __shared__ float As[BK][BM];   // transposed A tile
  __shared__ float Bs[BK][BN];
  const int tid = threadIdx.x;
  const int bm = blockIdx.y * BM;
  const int bn = blockIdx.x * BN;
  const int tm = (tid >> 4) * TM;
  const int tn = (tid & 15) * TN;
  float acc[TM][TN] = {};
  for (int k0 = 0; k0 < K; k0 += BK) {
    // A tile: 128x16 = 512 float4, 2 per thread (32B contiguous per thread)
    #pragma unroll
    for (int i = 0; i < 2; ++i) {
      int idx = tid * 2 + i;
      int r = idx >> 2, c4 = idx & 3;
      float4 a = *(const float4*)(A + (size_t)(bm + r) * K + k0 + c4 * 4);
      As[c4 * 4 + 0][r] = a.x;
      As[c4 * 4 + 1][r] = a.y;
      As[c4 * 4 + 2][r] = a.z;
      As[c4 * 4 + 3][r] = a.w;
    }
    // B tile: 16x128 = 512 float4, 2 per thread
    #pragma unroll
    for (int i = 0; i < 2; ++i) {
      int idx = tid * 2 + i;
      int r = idx >> 5, c4 = idx & 31;
      *(float4*)&Bs[r][c4 * 4] = *(const float4*)(B + (size_t)(k0 + r) * N + bn + c4 * 4);
    }
    __syncthreads();
    #pragma unroll
    for (int kk = 0; kk < BK; ++kk) {
      float ar[TM], br[TN];
      *(float4*)&ar[0] = *(const float4*)&As[kk][tm];
      *(float4*)&ar[4] = *(const float4*)&As[kk][tm + 4];
      *(float4*)&br[0] = *(const float4*)&Bs[kk][tn];
      *(float4*)&br[4] = *(const float4*)&Bs[kk][tn + 4];
      #pragma unroll
      for (int i = 0; i < TM; ++i)
        #pragma unroll
        for (int j = 0; j < TN; ++j)
          acc[i][j] = fmaf(ar[i], br[j], acc[i][j]);
    }
    __syncthreads();
  }
  #pragma unroll
  for (int i = 0; i < TM; ++i) {
    float* crow = C + (size_t)(bm + tm + i) * N + bn + tn;
    #pragma unroll
    for (int j = 0; j < TN; j += 4) {
      float4 v;
      v.x = acc[i][j + 0] + bias[bn + tn + j + 0];
      v.y = acc[i][j + 1] + bias[bn + tn + j + 1];
      v.z = acc[i][j + 2] + bias[bn + tn + j + 2];
      v.w = acc[i][j + 3] + bias[bn + tn + j + 3];
      *(float4*)(crow + j) = v;
    }
  }
}

// ---------------------------------------------------------------------------
// Persistent LSTM scan. 256 wgs x 256 threads = 1024 waves, one hidden unit
// per wave. Each lane: gate g = lane/16, h-partition p = lane%16; holds 64
// W_hh weights in VGPRs for the whole scan. Sync across wgs is NaN-sentinel
// dataflow on the h history buffer (each element written exactly once with a
// system-scope store; consumers poll with L2-bypassing loads). No LDS, no
// __syncthreads, no flags. Co-residency: 256 wgs over 256 CUs, ~200 VGPR,
// no LDS -> trivially all resident.
// ---------------------------------------------------------------------------
__global__ __launch_bounds__(256, 1) void lstm_scan_kernel(
    const float* __restrict__ xg,    // [T][4096], bias already folded in
    const float* __restrict__ Whh,   // [H][4096]
    float* __restrict__ hout,        // [T][H], pre-filled with NaN sentinel
    int nsteps)
{
  const int w = threadIdx.x >> 6;   // wave in block -> unit offset
  const int l = threadIdx.x & 63;
  const int g = l >> 4;             // gate 0..3 (i,f,g,o)
  const int p = l & 15;             // h partition
  const int u = blockIdx.x * 4 + w; // hidden unit 0..1023
  const int col = g * HH + u;       // gate column in [0,4096)

  // Preload this lane's 64 weights: rows 4*(p+16k)+e, k=0..15, e=0..3.
  float wr[64];
  #pragma unroll
  for (int k = 0; k < 16; ++k) {
    #pragma unroll
    for (int e = 0; e < 4; ++e) {
      wr[4 * k + e] = Whh[(size_t)(4 * (p + 16 * k) + e) * G4 + col];
    }
  }

  float c = 0.0f;
  float xgv = xg[col];              // prefetched xg for current t (row 0)
  uint32_t budget = (1u << 21);     // anti-hang safety valve

  for (int t = 0; t < nsteps; ++t) {
    float xg_cur = xgv;
    int tnext = (t + 1 < nsteps) ? t + 1 : t;
    xgv = xg[(size_t)tnext * G4 + col];   // prefetch next step's xg

    float red = 0.0f;
    if (t > 0) {
      const float* hrow = hout + (size_t)(t - 1) * HH;
      const float* a0 = hrow + p * 4;  // lane reads chunks p+16k (coalesced, 4-way bcast)
      f32x4 hv[16];
      int done = 0;
      do {
        asm volatile(
          "global_load_dwordx4 %0,  %16, off sc0 sc1\n\t"
          "global_load_dwordx4 %1,  %16, off offset:256 sc0 sc1\n\t"
          "global_load_dwordx4 %2,  %16, off offset:512 sc0 sc1\n\t"
          "global_load_dwordx4 %3,  %16, off offset:768 sc0 sc1\n\t"
          "global_load_dwordx4 %4,  %16, off offset:1024 sc0 sc1\n\t"
          "global_load_dwordx4 %5,  %16, off offset:1280 sc0 sc1\n\t"
          "global_load_dwordx4 %6,  %16, off offset:1536 sc0 sc1\n\t"
          "global_load_dwordx4 %7,  %16, off offset:1792 sc0 sc1\n\t"
          "global_load_dwordx4 %8,  %16, off offset:2048 sc0 sc1\n\t"
          "global_load_dwordx4 %9,  %16, off offset:2304 sc0 sc1\n\t"
          "global_load_dwordx4 %10, %16, off offset:2560 sc0 sc1\n\t"
          "global_load_dwordx4 %11, %16, off offset:2816 sc0 sc1\n\t"
          "global_load_dwordx4 %12, %16, off offset:3072 sc0 sc1\n\t"
          "global_load_dwordx4 %13, %16, off offset:3328 sc0 sc1\n\t"
          "global_load_dwordx4 %14, %16, off offset:3584 sc0 sc1\n\t"
          "global_load_dwordx4 %15, %16, off offset:3840 sc0 sc1"
          : "=v"(hv[0]), "=v"(hv[1]), "=v"(hv[2]), "=v"(hv[3]),
            "=v"(hv[4]), "=v"(hv[5]), "=v"(hv[6]), "=v"(hv[7]),
            "=v"(hv[8]), "=v"(hv[9]), "=v"(hv[10]), "=v"(hv[11]),
            "=v"(hv[12]), "=v"(hv[13]), "=v"(hv[14]), "=v"(hv[15])
          : "v"(a0));
        asm volatile("s_waitcnt vmcnt(0)" ::: "memory");
        __builtin_amdgcn_sched_barrier(0);  // rule #18: don't hoist uses past waitcnt
        int valid = 1;
        #pragma unroll
        for (int k = 0; k < 16; ++k) {
          valid &= (__float_as_uint(hv[k].x) != SENT);
          valid &= (__float_as_uint(hv[k].y) != SENT);
          valid &= (__float_as_uint(hv[k].z) != SENT);
          valid &= (__float_as_uint(hv[k].w) != SENT);
        }
        done = __all(valid);
        if (!done) --budget;
      } while (!done && budget);
      if (!done) {
        // Safety valve: zero remaining sentinels so we terminate (validation
        // will then fail loudly instead of the bench hanging).
        #pragma unroll
        for (int k = 0; k < 16; ++k) {
          if (__float_as_uint(hv[k].x) == SENT) hv[k].x = 0.0f;
          if (__float_as_uint(hv[k].y) == SENT) hv[k].y = 0.0f;
          if (__float_as_uint(hv[k].z) == SENT) hv[k].z = 0.0f;
          if (__float_as_uint(hv[k].w) == SENT) hv[k].w = 0.0f;
        }
      }
      // 64 MACs, 4 independent chains for ILP
      float s0 = 0.f, s1 = 0.f, s2 = 0.f, s3 = 0.f;
      #pragma unroll
      for (int k = 0; k < 16; ++k) {
        s0 = fmaf(wr[4 * k + 0], hv[k].x, s0);
        s1 = fmaf(wr[4 * k + 1], hv[k].y, s1);
        s2 = fmaf(wr[4 * k + 2], hv[k].z, s2);
        s3 = fmaf(wr[4 * k + 3], hv[k].w, s3);
      }
      red = (s0 + s1) + (s2 + s3);
      // reduce over 16-lane partition group (aligned, so xor masks 1..8 stay in group)
      #pragma unroll
      for (int m = 1; m < 16; m <<= 1) red += __shfl_xor(red, m, 64);
    }

    float gp = red + xg_cur;              // full pre-activation for (gate g, unit u)
    float gi_ = __shfl(gp, 0, 64);        // gate i (lanes 0-15 group)
    float gf_ = __shfl(gp, 16, 64);       // gate f
    float gg_ = __shfl(gp, 32, 64);       // gate g
    float go_ = __shfl(gp, 48, 64);       // gate o
    float iv = sigf(gi_);
    float fv = sigf(gf_);
    float gv = tanhf(gg_);
    float ov = sigf(go_);
    c = fv * c + iv * gv;                 // replicated identically across all 64 lanes
    float h = ov * tanhf(c);
    if (l == 0) {
      __hip_atomic_store(hout + (size_t)t * HH + u, h,
                         __ATOMIC_RELAXED, __HIP_MEMORY_SCOPE_SYSTEM);
    }
  }
}

// ---------------------------------------------------------------------------
extern "C" void kernel_launch(void* const* d_in, const int* in_sizes, int n_in,
                              void* d_out, int out_size, void* d_ws, size_t ws_size,
                              hipStream_t stream)
{
  const float* x    = (const float*)d_in[0];
  const float* Wih0 = (const float*)d_in[1];
  const float* Whh0 = (const float*)d_in[2];
  const float* b0   = (const float*)d_in[3];
  const float* Wih1 = (const float*)d_in[4];
  const float* Whh1 = (const float*)d_in[5];
  const float* b1   = (const float*)d_in[6];
  float* out = (float*)d_out;

  float* ws    = (float*)d_ws;
  float* xgbuf = ws;                        // TT*G4 floats (128 MB), reused by both layers
  float* h1    = ws + (size_t)TT * G4;      // TT*HH floats (32 MB)

  // 1. sentinel init of both h histories
  nan_fill_kernel<<<2048, 256, 0, stream>>>(h1, (long)TT * HH);
  nan_fill_kernel<<<2048, 256, 0, stream>>>(out, (long)TT * HH);

  dim3 gblk(256);
  dim3 ggrid(G4 / 128, TT / 128);

  // 2. xg = x @ W_ih_0 + b_0
  gemm_bias_f32<<<ggrid, gblk, 0, stream>>>(x, Wih0, b0, xgbuf, TT, G4, INDIM);
  // 3. layer-0 scan -> h1
  lstm_scan_kernel<<<256, 256, 0, stream>>>(xgbuf, Whh0, h1, TT);
  // 4. xg = h1 @ W_ih_1 + b_1
  gemm_bias_f32<<<ggrid, gblk, 0, stream>>>(h1, Wih1, b1, xgbuf, TT, G4, HH);
  // 5. layer-1 scan -> d_out (d_out IS the h2 history)
  lstm_scan_kernel<<<256, 256, 0, stream>>>(xgbuf, Whh1, out, TT);
}